// Round 1
// 281.164 us; speedup vs baseline: 1.0178x; 1.0178x over previous
//
#include <hip/hip_runtime.h>
#include <hip/hip_bf16.h>

#define B_ 16
#define T_ 16384
#define C_ 8
#define L_ 16384
#define W_ 256
#define R_ 32

typedef __bf16 bf16x8 __attribute__((ext_vector_type(8)));
typedef float f32x4 __attribute__((ext_vector_type(4)));

// ---------------------------------------------------------------------------
// Kernel 1: x (B,T,C) fp32  ->  xt (B,C,L) bf16
// ---------------------------------------------------------------------------
__global__ void xconv_kernel(const float* __restrict__ x,
                             unsigned short* __restrict__ xt) {
  unsigned idx = blockIdx.x * 256u + threadIdx.x;   // [0, B*C*L) = 2^21
  unsigned t = idx & (L_ - 1);
  unsigned c = (idx >> 14) & (C_ - 1);
  unsigned b = idx >> 17;
  float v = x[((size_t)b * T_ + t) * C_ + c];
  __bf16 h = (__bf16)v;   // RTNE
  xt[idx] = __builtin_bit_cast(unsigned short, h);
}

// ---------------------------------------------------------------------------
// Kernel 2: Gabor bank -> Fg[c][j][w] bf16, j in [0,64): j<32 real(r=j),
// j>=32 imag(r=j-32); param index = c*32 + (31 - r)  (bakes the [::-1])
// ---------------------------------------------------------------------------
__global__ void gen_filters_kernel(const float* __restrict__ kv,
                                   const float* __restrict__ sv,
                                   unsigned short* __restrict__ Fg) {
  unsigned idx = blockIdx.x * 256u + threadIdx.x;   // [0, 8*64*256)
  unsigned w = idx & (W_ - 1);
  unsigned j = (idx >> 8) & 63u;
  unsigned c = idx >> 14;
  unsigned r = j & 31u;
  unsigned pidx = c * 32u + (31u - r);
  float k  = kv[pidx];
  float sg = sv[pidx];
  float phase = (-6.283185307179586f / (float)W_) * k * (float)w;
  float dn = (float)w - (float)(W_ / 2);
  float var2 = 2.0f * sg * sg;                       // 2*sigma^2
  float g = (1.0f / sqrtf(3.14159265358979f * var2)) * expf(-(dn * dn) / var2);
  float s, cth;
  sincosf(phase, &s, &cth);
  float v = (j < 32u) ? cth * g : s * g;
  __bf16 h = (__bf16)v;
  Fg[idx] = __builtin_bit_cast(unsigned short, h);
}

// ---------------------------------------------------------------------------
// Kernel 3: main MFMA kernel.
// Block = 256 threads = 4 waves (2 wm x 2 wn), handles (b, c, 256 t-rows).
// Wave (wm,wn): rows [wm*128, wm*128+128) x output cols [wn*16, wn*16+16),
// computing real (filter rows wn*16+lrow) and imag (filter rows +32) in
// acc[mt][0] / acc[mt][1].
//
// A is Toeplitz: A[t][k] = xwin[t+k].  LDS table atab[s] = xwin[s..s+7]
// (16B entry at byte 16*s) makes every A fragment ONE aligned ds_read_b128
// at base + 256*(mt + 2*kk).  Fragments are shared along diagonals
// p = mt + 2*kk -> only 22 distinct A loads per wave (rotating 8-reg window).
// ---------------------------------------------------------------------------
__global__ __launch_bounds__(256, 2) void wavelet_main_kernel(
    const unsigned short* __restrict__ xt,   // [B][C][L] bf16
    const unsigned short* __restrict__ Fg,   // [C][64][256] bf16
    float* __restrict__ out)                 // [B][L][256] fp32
{
  // 64 filter rows, 256 bf16 each, padded to 264 bf16 (132 dwords) per row
  __shared__ __align__(16) unsigned int Fs[64 * 132];   // 33792 B
  __shared__ __align__(16) uint4 atab[512];             // 8192 B sliding window

  const int tid = threadIdx.x;
  const unsigned bid = blockIdx.x;
  const int tb = bid & 63;           // 64 t-blocks per (b,c)
  const int c  = (bid >> 6) & 7;
  const int b  = bid >> 9;
  const int t0 = tb << 8;            // 256 t per block

  // ---- stage filters: 64x256 bf16 = 2048 uint4 ----
  {
    const uint4* Fg4 = reinterpret_cast<const uint4*>(Fg + (size_t)c * (64 * 256));
    #pragma unroll
    for (int it = 0; it < 8; ++it) {
      int i = it * 256 + tid;
      uint4 v = Fg4[i];
      int j  = i >> 5;              // 32 uint4 per 256-bf16 row
      int wq = (i & 31) << 2;       // dword offset within row
      *reinterpret_cast<uint4*>(&Fs[j * 132 + wq]) = v;
    }
  }

  // ---- build sliding-window table: atab[s] = xwin[s..s+7], s in [0,512) ----
  // xwin[i] = x[b,c, t0-128+i], zero-padded outside [0,L)
  {
    const unsigned short* xrow = xt + ((size_t)b * C_ + c) * L_;
    const int g0 = t0 - 128 + 2 * tid;   // global index of xwin[2*tid]
    unsigned e0, e1, e2, e3, e4;
    {
      int g;
      g = g0;     e0 = (g >= 0 && g <= L_ - 2) ? *reinterpret_cast<const unsigned*>(xrow + g) : 0u;
      g = g0 + 2; e1 = (g >= 0 && g <= L_ - 2) ? *reinterpret_cast<const unsigned*>(xrow + g) : 0u;
      g = g0 + 4; e2 = (g >= 0 && g <= L_ - 2) ? *reinterpret_cast<const unsigned*>(xrow + g) : 0u;
      g = g0 + 6; e3 = (g >= 0 && g <= L_ - 2) ? *reinterpret_cast<const unsigned*>(xrow + g) : 0u;
      g = g0 + 8; e4 = (g >= 0 && g <= L_ - 2) ? *reinterpret_cast<const unsigned*>(xrow + g) : 0u;
    }
    uint4 ev;  // entry s = 2*tid   : xwin[2t .. 2t+7]
    ev.x = e0; ev.y = e1; ev.z = e2; ev.w = e3;
    uint4 od;  // entry s = 2*tid+1 : xwin[2t+1 .. 2t+8]  (funnel shift by 16)
    od.x = (e0 >> 16) | (e1 << 16);
    od.y = (e1 >> 16) | (e2 << 16);
    od.z = (e2 >> 16) | (e3 << 16);
    od.w = (e3 >> 16) | (e4 << 16);
    atab[2 * tid]     = ev;
    atab[2 * tid + 1] = od;
  }
  __syncthreads();

  const int lane = tid & 63;
  const int wv   = tid >> 6;
  const int wm   = wv >> 1;          // row half: 0 or 1 (128 rows each)
  const int wn   = wv & 1;           // col half: 0 or 1 (16 output cols each)
  const int quad = lane >> 4;
  const int lrow = lane & 15;

  // A fragment base: entry index (wm*128 + lrow + quad*8); fragment p adds 16*p
  const uint4* tabp = atab + (wm * 128 + lrow + quad * 8);
  // B fragment bases: filter row wn*16+lrow (real) and +32 (imag)
  const unsigned int* fs0 = &Fs[(wn * 16 + lrow) * 132 + quad * 4];
  const unsigned int* fs1 = &Fs[(wn * 16 + lrow + 32) * 132 + quad * 4];

  f32x4 acc[8][2];
  #pragma unroll
  for (int mt = 0; mt < 8; ++mt) {
    acc[mt][0] = (f32x4){0.f, 0.f, 0.f, 0.f};
    acc[mt][1] = (f32x4){0.f, 0.f, 0.f, 0.f};
  }

  // rotating window of A fragments: slot (p & 7) holds diagonal p
  bf16x8 af[8];
  #pragma unroll
  for (int p = 0; p < 8; ++p)
    af[p] = __builtin_bit_cast(bf16x8, tabp[16 * p]);

  #pragma unroll
  for (int kk = 0; kk < 8; ++kk) {
    if (kk) {
      af[(2 * kk + 6) & 7] = __builtin_bit_cast(bf16x8, tabp[16 * (2 * kk + 6)]);
      af[(2 * kk + 7) & 7] = __builtin_bit_cast(bf16x8, tabp[16 * (2 * kk + 7)]);
    }
    const bf16x8 bfr0 = __builtin_bit_cast(bf16x8,
        *reinterpret_cast<const uint4*>(fs0 + kk * 16));
    const bf16x8 bfr1 = __builtin_bit_cast(bf16x8,
        *reinterpret_cast<const uint4*>(fs1 + kk * 16));
    #pragma unroll
    for (int mt = 0; mt < 8; ++mt) {
      acc[mt][0] = __builtin_amdgcn_mfma_f32_16x16x32_bf16(
          af[(2 * kk + mt) & 7], bfr0, acc[mt][0], 0, 0, 0);
      acc[mt][1] = __builtin_amdgcn_mfma_f32_16x16x32_bf16(
          af[(2 * kk + mt) & 7], bfr1, acc[mt][1], 0, 0, 0);
    }
  }

  // ---- epilogue: power = real^2 + imag^2 ----
  // D layout: row = quad*4 + i, col = lrow (per 16x16 tile).
  // Output col = c*32 + wn*16 + lrow; one float per (mt,i).
  const size_t obase = (size_t)b * ((size_t)L_ * 256)
                     + (size_t)(c * 32 + wn * 16 + lrow);
  #pragma unroll
  for (int mt = 0; mt < 8; ++mt) {
    #pragma unroll
    for (int i = 0; i < 4; ++i) {
      const int t = t0 + wm * 128 + mt * 16 + quad * 4 + i;
      out[obase + (size_t)t * 256] =
          acc[mt][0][i] * acc[mt][0][i] + acc[mt][1][i] * acc[mt][1][i];
    }
  }
}

// ---------------------------------------------------------------------------
extern "C" void kernel_launch(void* const* d_in, const int* in_sizes, int n_in,
                              void* d_out, int out_size, void* d_ws, size_t ws_size,
                              hipStream_t stream) {
  const float* x  = (const float*)d_in[0];
  const float* kv = (const float*)d_in[1];
  const float* sv = (const float*)d_in[2];
  float* out = (float*)d_out;

  unsigned short* xt = (unsigned short*)d_ws;                 // B*C*L bf16 = 4 MB
  unsigned short* Fg = xt + (size_t)B_ * C_ * L_;             // 8*64*256 bf16 = 256 KB

  hipLaunchKernelGGL(xconv_kernel, dim3((B_ * C_ * L_) / 256), dim3(256), 0, stream,
                     x, xt);
  hipLaunchKernelGGL(gen_filters_kernel, dim3((C_ * 64 * W_) / 256), dim3(256), 0, stream,
                     kv, sv, Fg);
  hipLaunchKernelGGL(wavelet_main_kernel, dim3(B_ * C_ * (L_ / 256)), dim3(256), 0, stream,
                     xt, Fg, out);
}